// Round 15
// baseline (181.626 us; speedup 1.0000x reference)
//
#include <hip/hip_runtime.h>
#include <hip/hip_bf16.h>

// ---------------- common types / helpers ----------------
typedef __bf16 bf16x8 __attribute__((ext_vector_type(8)));
typedef float  f32x4  __attribute__((ext_vector_type(4)));
typedef float  f32x16 __attribute__((ext_vector_type(16)));
typedef unsigned int uint4v __attribute__((ext_vector_type(4)));

__device__ __forceinline__ unsigned short f2bf(float f){
  union { float f; unsigned int u; } v; v.f = f;
  unsigned int r = (v.u + 0x7FFFu + ((v.u >> 16) & 1u)) >> 16;
  return (unsigned short)r;
}

__device__ __forceinline__ float bf2f(unsigned short u){
  union { unsigned int i; float f; } v; v.i = ((unsigned int)u) << 16; return v.f;
}

__device__ __forceinline__ unsigned pkbf(float a, float b){
  unsigned r;
  asm("v_cvt_pk_bf16_f32 %0, %1, %2" : "=v"(r) : "v"(a), "v"(b));
  return r;
}

__device__ __forceinline__ void gload_lds16(const void* g, void* l){
  __builtin_amdgcn_global_load_lds(
      (const __attribute__((address_space(1))) unsigned int*)g,
      (__attribute__((address_space(3))) unsigned int*)l, 16, 0, 0);
}

#define MFMA16(a,b,c) __builtin_amdgcn_mfma_f32_16x16x32_bf16((a),(b),(c),0,0,0)
#define MFMA32(a,b,c) __builtin_amdgcn_mfma_f32_32x32x16_bf16((a),(b),(c),0,0,0)

// ---------------- fused: x->bf16, weights->bf16, AND xB (last 32 rows) ----------------
__global__ void k_conv(const float* __restrict__ x,
                       const float* __restrict__ Wq, const float* __restrict__ Wk,
                       const float* __restrict__ Wv, const float* __restrict__ Wo,
                       const float* __restrict__ Wr, const float* __restrict__ Bs,
                       unsigned short* __restrict__ xb16,
                       unsigned short* __restrict__ wqkv, unsigned short* __restrict__ wo,
                       unsigned short* __restrict__ wrt, float* __restrict__ xbt){
  int bid = blockIdx.x;
  if (bid >= 5632){
    int bb = (bid - 5632) >> 5, t = (bid - 5632) & 31;
    int tid = threadIdx.x, n = tid & 63, p = tid >> 6;
    const float* xr = x + ((long)bb * 2048 + 2016 + t) * 1024 + p * 256;
    const float* Bp = Bs + (p * 256) * 64 + n;
    float a0 = 0.f, a1 = 0.f, a2 = 0.f, a3 = 0.f;
    #pragma unroll 4
    for (int d = 0; d < 256; d += 4){
      float4 xv = *reinterpret_cast<const float4*>(xr + d);
      a0 += xv.x * Bp[(d    ) * 64];
      a1 += xv.y * Bp[(d + 1) * 64];
      a2 += xv.z * Bp[(d + 2) * 64];
      a3 += xv.w * Bp[(d + 3) * 64];
    }
    __shared__ float red[4][64];
    red[p][n] = (a0 + a1) + (a2 + a3);
    __syncthreads();
    if (tid < 64){
      float s = red[0][tid] + red[1][tid] + red[2][tid] + red[3][tid];
      xbt[(bb * 32 + t) * 64 + tid] = s;
    }
    return;
  }
  if (bid < 4096){
    int i = (bid * 256 + threadIdx.x) * 4;
    float4 v = *reinterpret_cast<const float4*>(x + i);
    ushort4 r; r.x = f2bf(v.x); r.y = f2bf(v.y); r.z = f2bf(v.z); r.w = f2bf(v.w);
    *reinterpret_cast<ushort4*>(xb16 + i) = r;
    return;
  }
  int j = ((bid - 4096) * 256 + threadIdx.x) * 4;
  if (j < 393216){
    const float* s;
    if (j < 131072) s = Wq + j; else if (j < 262144) s = Wk + (j - 131072); else s = Wv + (j - 262144);
    float4 v = *reinterpret_cast<const float4*>(s);
    ushort4 r; r.x = f2bf(v.x); r.y = f2bf(v.y); r.z = f2bf(v.z); r.w = f2bf(v.w);
    *reinterpret_cast<ushort4*>(wqkv + j) = r;
  } else if (j < 1441792){
    int jj = j - 393216;
    float4 v = *reinterpret_cast<const float4*>(Wo + jj);
    ushort4 r; r.x = f2bf(v.x); r.y = f2bf(v.y); r.z = f2bf(v.z); r.w = f2bf(v.w);
    *reinterpret_cast<ushort4*>(wo + jj) = r;
  } else {
    int jj = j - 1441792;
    int n = jj >> 10, d = jj & 1023;
    ushort4 r;
    if (n < 64){
      float4 v = *reinterpret_cast<const float4*>(Wr + n * 1024 + d);
      r.x = f2bf(v.x); r.y = f2bf(v.y); r.z = f2bf(v.z); r.w = f2bf(v.w);
    } else { r.x = 0; r.y = 0; r.z = 0; r.w = 0; }
    *reinterpret_cast<ushort4*>(wrt + jj) = r;
  }
}

// ---------------- generic bf16 GEMM: C[M,N] = A[M,K] * Bt[N,K]^T (128x128) ----------------
template<int CBF16>
__global__ __launch_bounds__(256) void k_gemm(
    const unsigned short* __restrict__ A, const unsigned short* __restrict__ Bt,
    void* __restrict__ Cv, int M, int N, int K,
    long sA, long sB, long sC)
{
  __shared__ __align__(16) unsigned short Al[128 * 64];
  __shared__ __align__(16) unsigned short Bl[128 * 64];
  const int tid = threadIdx.x, wv = tid >> 6, lane = tid & 63;
  const int bm = blockIdx.y * 128, bn = blockIdx.x * 128, z = blockIdx.z;
  const unsigned short* Ab = A + (long)z * sA;
  const unsigned short* Bb = Bt + (long)z * sB;
  const f32x4 zero = {0.f, 0.f, 0.f, 0.f};
  f32x4 acc[4][4];
  #pragma unroll
  for (int i = 0; i < 4; ++i)
    #pragma unroll
    for (int j = 0; j < 4; ++j) acc[i][j] = zero;
  const int mo = (wv & 1) * 64, no = (wv >> 1) * 64;

  for (int k0 = 0; k0 < K; k0 += 64){
    __syncthreads();
    #pragma unroll
    for (int i = 0; i < 4; ++i){
      int rr = (wv * 4 + i) * 8 + (lane >> 3);
      gload_lds16(Ab + (long)(bm + rr) * K + k0 + (lane & 7) * 8, &Al[(wv * 4 + i) * 8 * 64]);
      gload_lds16(Bb + (long)(bn + rr) * K + k0 + (lane & 7) * 8, &Bl[(wv * 4 + i) * 8 * 64]);
    }
    __syncthreads();
    #pragma unroll
    for (int ks = 0; ks < 2; ++ks){
      bf16x8 af[4], bfr[4];
      #pragma unroll
      for (int mi = 0; mi < 4; ++mi)
        af[mi] = *reinterpret_cast<const bf16x8*>(&Al[(mo + mi * 16 + (lane & 15)) * 64 + ks * 32 + (lane >> 4) * 8]);
      #pragma unroll
      for (int ni = 0; ni < 4; ++ni)
        bfr[ni] = *reinterpret_cast<const bf16x8*>(&Bl[(no + ni * 16 + (lane & 15)) * 64 + ks * 32 + (lane >> 4) * 8]);
      #pragma unroll
      for (int mi = 0; mi < 4; ++mi)
        #pragma unroll
        for (int ni = 0; ni < 4; ++ni)
          acc[mi][ni] = MFMA16(af[mi], bfr[ni], acc[mi][ni]);
    }
  }

  #pragma unroll
  for (int mi = 0; mi < 4; ++mi)
    #pragma unroll
    for (int ni = 0; ni < 4; ++ni)
      #pragma unroll
      for (int r = 0; r < 4; ++r){
        int row = bm + mo + mi * 16 + (lane >> 4) * 4 + r;
        int col = bn + no + ni * 16 + (lane & 15);
        float v = acc[mi][ni][r];
        if (CBF16) ((unsigned short*)Cv)[(long)z * sC + (long)row * N + col] = f2bf(v);
        else       ((float*)Cv)[(long)z * sC + (long)row * N + col] = v;
      }
}

// ---------------- 128x64-tile GEMM, f32 out (out-projection) ----------------
__global__ __launch_bounds__(256) void k_gemm64(
    const unsigned short* __restrict__ A, const unsigned short* __restrict__ Bt,
    float* __restrict__ C, int M, int N, int K)
{
  __shared__ __align__(16) unsigned short Al[128 * 64];
  __shared__ __align__(16) unsigned short Bl[64 * 64];
  const int tid = threadIdx.x, wv = tid >> 6, lane = tid & 63;
  const int bm = blockIdx.y * 128, bn = blockIdx.x * 64;
  const f32x4 zero = {0.f, 0.f, 0.f, 0.f};
  f32x4 acc[4][2];
  #pragma unroll
  for (int i = 0; i < 4; ++i){ acc[i][0] = zero; acc[i][1] = zero; }
  const int mo = (wv & 1) * 64, no = (wv >> 1) * 32;

  for (int k0 = 0; k0 < K; k0 += 64){
    __syncthreads();
    #pragma unroll
    for (int i = 0; i < 4; ++i){
      int rr = (wv * 4 + i) * 8 + (lane >> 3);
      gload_lds16(A + (long)(bm + rr) * K + k0 + (lane & 7) * 8, &Al[(wv * 4 + i) * 8 * 64]);
    }
    #pragma unroll
    for (int i = 0; i < 2; ++i){
      int rr = (wv * 2 + i) * 8 + (lane >> 3);
      gload_lds16(Bt + (long)(bn + rr) * K + k0 + (lane & 7) * 8, &Bl[(wv * 2 + i) * 8 * 64]);
    }
    __syncthreads();
    #pragma unroll
    for (int ks = 0; ks < 2; ++ks){
      bf16x8 af[4], bfr[2];
      #pragma unroll
      for (int mi = 0; mi < 4; ++mi)
        af[mi] = *reinterpret_cast<const bf16x8*>(&Al[(mo + mi * 16 + (lane & 15)) * 64 + ks * 32 + (lane >> 4) * 8]);
      #pragma unroll
      for (int ni = 0; ni < 2; ++ni)
        bfr[ni] = *reinterpret_cast<const bf16x8*>(&Bl[(no + ni * 16 + (lane & 15)) * 64 + ks * 32 + (lane >> 4) * 8]);
      #pragma unroll
      for (int mi = 0; mi < 4; ++mi)
        #pragma unroll
        for (int ni = 0; ni < 2; ++ni)
          acc[mi][ni] = MFMA16(af[mi], bfr[ni], acc[mi][ni]);
    }
  }

  #pragma unroll
  for (int mi = 0; mi < 4; ++mi)
    #pragma unroll
    for (int ni = 0; ni < 2; ++ni)
      #pragma unroll
      for (int r = 0; r < 4; ++r){
        int row = bm + mo + mi * 16 + (lane >> 4) * 4 + r;
        int col = bn + no + ni * 16 + (lane & 15);
        C[(long)row * N + col] = acc[mi][ni][r];
      }
}

// ---------------- split-K GEMM: f32 partials, 4 splits of K (+ optional fused scan layer) ----------------
__global__ __launch_bounds__(256) void k_gemmsk(
    const unsigned short* __restrict__ A, const unsigned short* __restrict__ Bt,
    float* __restrict__ P, int M, int N, int Kfull, int KS,
    long sA, long sB,
    int do_scan, const float* __restrict__ xbt, const float* __restrict__ Asc,
    float* __restrict__ hfin)
{
  __shared__ __align__(16) unsigned short Al[128 * 64];
  __shared__ __align__(16) unsigned short Bl[128 * 64];
  const int tid = threadIdx.x, wv = tid >> 6, lane = tid & 63;

  if (do_scan && blockIdx.z == 4){
    if (blockIdx.y < 2 && tid < 64){
      int b = blockIdx.y, j = tid;
      float Ac[64];
      #pragma unroll
      for (int i = 0; i < 64; ++i) Ac[i] = Asc[i * 64 + j];
      float* xs = (float*)Al;
      float* hs = xs + 2048;
      #pragma unroll
      for (int t = 0; t < 32; ++t) xs[t * 64 + j] = xbt[(b * 32 + t) * 64 + j];
      hs[j] = xs[j];
      for (int t = 1; t < 32; ++t){
        float a0 = 0.f, a1 = 0.f, a2 = 0.f, a3 = 0.f;
        #pragma unroll
        for (int ii = 0; ii < 16; ++ii){
          float4 h4 = *reinterpret_cast<const float4*>(&hs[ii * 4]);
          a0 += h4.x * Ac[ii * 4 + 0];
          a1 += h4.y * Ac[ii * 4 + 1];
          a2 += h4.z * Ac[ii * 4 + 2];
          a3 += h4.w * Ac[ii * 4 + 3];
        }
        hs[j] = (a0 + a1) + (a2 + a3) + xs[t * 64 + j];
      }
      hfin[b * 64 + j] = hs[j];
    }
    return;
  }

  const int bm = blockIdx.y * 128, bn = blockIdx.x * 128, z = blockIdx.z;
  const int b = z >> 2, s = z & 3;
  const unsigned short* Ab = A + (long)b * sA;
  const unsigned short* Bb = Bt + (long)b * sB;
  float* Pb = P + (long)z * M * N;
  const f32x4 zero = {0.f, 0.f, 0.f, 0.f};
  f32x4 acc[4][4];
  #pragma unroll
  for (int i = 0; i < 4; ++i)
    #pragma unroll
    for (int j = 0; j < 4; ++j) acc[i][j] = zero;
  const int mo = (wv & 1) * 64, no = (wv >> 1) * 64;

  const int k1 = s * KS + KS;
  for (int k0 = s * KS; k0 < k1; k0 += 64){
    __syncthreads();
    #pragma unroll
    for (int i = 0; i < 4; ++i){
      int rr = (wv * 4 + i) * 8 + (lane >> 3);
      gload_lds16(Ab + (long)(bm + rr) * Kfull + k0 + (lane & 7) * 8, &Al[(wv * 4 + i) * 8 * 64]);
      gload_lds16(Bb + (long)(bn + rr) * Kfull + k0 + (lane & 7) * 8, &Bl[(wv * 4 + i) * 8 * 64]);
    }
    __syncthreads();
    #pragma unroll
    for (int ks = 0; ks < 2; ++ks){
      bf16x8 af[4], bfr[4];
      #pragma unroll
      for (int mi = 0; mi < 4; ++mi)
        af[mi] = *reinterpret_cast<const bf16x8*>(&Al[(mo + mi * 16 + (lane & 15)) * 64 + ks * 32 + (lane >> 4) * 8]);
      #pragma unroll
      for (int ni = 0; ni < 4; ++ni)
        bfr[ni] = *reinterpret_cast<const bf16x8*>(&Bl[(no + ni * 16 + (lane & 15)) * 64 + ks * 32 + (lane >> 4) * 8]);
      #pragma unroll
      for (int mi = 0; mi < 4; ++mi)
        #pragma unroll
        for (int ni = 0; ni < 4; ++ni)
          acc[mi][ni] = MFMA16(af[mi], bfr[ni], acc[mi][ni]);
    }
  }

  #pragma unroll
  for (int mi = 0; mi < 4; ++mi)
    #pragma unroll
    for (int ni = 0; ni < 4; ++ni)
      #pragma unroll
      for (int r = 0; r < 4; ++r){
        int row = bm + mo + mi * 16 + (lane >> 4) * 4 + r;
        int col = bn + no + ni * 16 + (lane & 15);
        Pb[(long)row * N + col] = acc[mi][ni][r];
      }
}

// ---------------- reduce hcomp partials (4 splits) -> bf16 ----------------
__global__ __launch_bounds__(256) void k_hred(const float* __restrict__ hpp,
                                              unsigned short* __restrict__ hcomp){
  int i4 = (blockIdx.x * 256 + threadIdx.x) * 4;
  int b = i4 >> 18;
  int rem = i4 & 262143;
  const float* p = hpp + (long)(b * 4) * 262144 + rem;
  f32x4 v = *reinterpret_cast<const f32x4*>(p);
  v += *reinterpret_cast<const f32x4*>(p + 262144);
  v += *reinterpret_cast<const f32x4*>(p + 524288);
  v += *reinterpret_cast<const f32x4*>(p + 786432);
  ushort4 o; o.x = f2bf(v[0]); o.y = f2bf(v[1]); o.z = f2bf(v[2]); o.w = f2bf(v[3]);
  *reinterpret_cast<ushort4*>(hcomp + (long)b * 262144 + rem) = o;
}

// ---------------- importance logits (with fused h_proj recompute per block) ----------------
__global__ __launch_bounds__(256) void k_logits(const float* __restrict__ x,
                                                const float* __restrict__ hfin,
                                                const float* __restrict__ Wimp,
                                                float* __restrict__ l){
  int tid = threadIdx.x, lane = tid & 63, wv = tid >> 6;
  int rowbase = blockIdx.x * 16;
  int b = rowbase >> 11;
  __shared__ float hs[64];
  __shared__ float hpl[1024];
  if (tid < 64) hs[tid] = hfin[b * 64 + tid];
  __syncthreads();
  #pragma unroll
  for (int e = 0; e < 4; ++e){
    int d = tid * 4 + e;
    const float* wr = Wimp + (long)d * 64;
    float a0 = 0.f, a1 = 0.f, a2 = 0.f, a3 = 0.f;
    #pragma unroll
    for (int k = 0; k < 64; k += 4){
      float4 w4 = *reinterpret_cast<const float4*>(wr + k);
      float4 h4 = *reinterpret_cast<const float4*>(&hs[k]);
      a0 += w4.x * h4.x; a1 += w4.y * h4.y; a2 += w4.z * h4.z; a3 += w4.w * h4.w;
    }
    hpl[d] = (a0 + a1) + (a2 + a3);
  }
  __syncthreads();
  float hp[16];
  #pragma unroll
  for (int i = 0; i < 16; ++i) hp[i] = hpl[i * 64 + lane];
  for (int rr = 0; rr < 4; ++rr){
    int row = rowbase + wv * 4 + rr;
    const float* xr = x + (long)row * 1024;
    float acc = 0.f;
    #pragma unroll
    for (int i = 0; i < 16; ++i) acc += xr[i * 64 + lane] * hp[i];
    #pragma unroll
    for (int o = 32; o; o >>= 1) acc += __shfl_xor(acc, o, 64);
    if (lane == 0) l[row] = acc;
  }
}

// ---------------- nw partials (fused importance softmax + router softmax weighting) ----------------
__global__ void k_nwpart(const float* __restrict__ rpp, const float* __restrict__ lbuf,
                         float* __restrict__ nwp){
  int bid = blockIdx.x; int b = bid >> 4, chunk = bid & 15;
  int tid = threadIdx.x, wv = tid >> 6, lane = tid & 63;
  __shared__ float wred[4], wsum[4];
  __shared__ float red[4][64];
  const float* lr = lbuf + b * 2048;
  float4 va = *reinterpret_cast<const float4*>(lr + tid * 8);
  float4 vb = *reinterpret_cast<const float4*>(lr + tid * 8 + 4);
  float mx8 = fmaxf(fmaxf(fmaxf(va.x, va.y), fmaxf(va.z, va.w)),
                    fmaxf(fmaxf(vb.x, vb.y), fmaxf(vb.z, vb.w)));
  #pragma unroll
  for (int o = 32; o; o >>= 1) mx8 = fmaxf(mx8, __shfl_xor(mx8, o, 64));
  if (lane == 0) wred[wv] = mx8;
  __syncthreads();
  float M = fmaxf(fmaxf(wred[0], wred[1]), fmaxf(wred[2], wred[3]));
  float se = __expf(va.x - M) + __expf(va.y - M) + __expf(va.z - M) + __expf(va.w - M)
           + __expf(vb.x - M) + __expf(vb.y - M) + __expf(vb.z - M) + __expf(vb.w - M);
  #pragma unroll
  for (int o = 32; o; o >>= 1) se += __shfl_xor(se, o, 64);
  if (lane == 0) wsum[wv] = se;
  __syncthreads();
  float inv = 1.f / (wsum[0] + wsum[1] + wsum[2] + wsum[3]);

  float accn = 0.f;
  for (int t = 0; t < 32; ++t){
    int s = chunk * 128 + wv * 32 + t;
    long off = ((long)b * 2048 + s) * 128 + lane;
    float v = rpp[off] + rpp[off + 524288] + rpp[off + 1048576] + rpp[off + 1572864];
    float mx = v;
    #pragma unroll
    for (int o = 32; o; o >>= 1) mx = fmaxf(mx, __shfl_xor(mx, o, 64));
    float e = __expf(v - mx);
    float sm = e;
    #pragma unroll
    for (int o = 32; o; o >>= 1) sm += __shfl_xor(sm, o, 64);
    float impv = __expf(lr[s] - M) * inv;
    accn += impv * (e / sm);
  }
  red[wv][lane] = accn;
  __syncthreads();
  if (wv == 0){
    float t = red[0][lane] + red[1][lane] + red[2][lane] + red[3][lane];
    nwp[bid * 64 + lane] = t;
  }
}

// ---------------- shared_compress^T (with fused nw normalization) ----------------
__global__ void k_sc(const float* __restrict__ cn, const float* __restrict__ nwp,
                     unsigned short* __restrict__ sct){
  int tid = threadIdx.x;
  long idx = (long)blockIdx.x * 256 + tid;
  int d = (int)(idx >> 5); int r0 = (int)(idx & 31) * 4;
  __shared__ float nws[128];
  if (tid < 128){
    int bb = tid >> 6, nn = tid & 63;
    float a = 0.f;
    #pragma unroll
    for (int c = 0; c < 16; ++c) a += nwp[(bb * 16 + c) * 64 + nn];
    float tot = a;
    #pragma unroll
    for (int o = 32; o; o >>= 1) tot += __shfl_xor(tot, o, 64);
    nws[tid] = a / (tot + 1e-8f);
  }
  __syncthreads();
  f32x4 a0 = {0.f,0.f,0.f,0.f}, a1 = {0.f,0.f,0.f,0.f};
  for (int n = 0; n < 64; ++n){
    f32x4 c = *reinterpret_cast<const f32x4*>(&cn[((long)n * 1024 + d) * 128 + r0]);
    a0 += nws[n] * c;
    a1 += nws[64 + n] * c;
  }
  #pragma unroll
  for (int e = 0; e < 4; ++e){
    sct[(long)(r0 + e) * 1024 + d]        = f2bf(a0[e]);
    sct[(long)(128 + r0 + e) * 1024 + d]  = f2bf(a1[e]);
  }
}

// ---------------- flash attention: 8-wave blocks (256 q rows), nspl-way KV split ----------------
// grid 256*nspl x 512 thr. Block = (g=(b,h), qpair in [0,8), part). Staging amortized
// over 8 waves (each wave: 1 K gload + 1 V uint4 + 8 ds_writes per tile).
// Per-wave compute core = round-9 proven 32x32 swapped-QK (tree softmax, 4-acc sum).
// Rule #20: all register-array loops have compile-time trip counts.
__global__ __launch_bounds__(512, 4) void k_attn(const unsigned short* __restrict__ qkv,
                                                 unsigned short* __restrict__ Op,
                                                 float* __restrict__ ml,
                                                 int nspl, int nsh){
  __shared__ __align__(16) unsigned short KlA[64 * 64];
  __shared__ __align__(16) unsigned short VtA[64 * 64];
  char* Kl = (char*)KlA;
  char* Vt = (char*)VtA;
  const int tid = threadIdx.x, w = tid >> 6, lane = tid & 63;
  const int l31 = lane & 31, hi = lane >> 5;
  const float CEXP = 0.18033688011112042f;  // 0.125 * log2(e)

  int li = blockIdx.x;
  int j = li & 7, m = li >> 3;
  int g = j * 4 + (m & 3);
  int r5 = m >> 2;                    // [0, 8*nspl)
  int k5 = r5 & 3, sel = r5 >> 2;     // sel [0, 2*nspl)
  int qpair = (sel < nspl) ? (7 - k5) : k5;
  int part = (sel < nspl) ? sel : (sel - nspl);
  int h = g & 15, b = g >> 4;
  int pidx = (g * 8 + qpair) * nspl + part;

  int T = 4 * qpair + 4;
  int t0 = (part * T) >> nsh;
  int t1 = ((part + 1) * T) >> nsh;

  int qbase = qpair * 256 + w * 32;
  int KTw = qbase >> 6;
  const unsigned short* base = qkv + (long)b * 2048 * 3072;

  bf16x8 qf[4];
  #pragma unroll
  for (int i = 0; i < 4; ++i)
    qf[i] = *reinterpret_cast<const bf16x8*>(base + (long)(qbase + l31) * 3072 + h * 64 + i * 16 + hi * 8);

  f32x16 oacc[2];
  #pragma unroll
  for (int d = 0; d < 2; ++d)
    #pragma unroll
    for (int r = 0; r < 16; ++r) oacc[d][r] = 0.f;
  float m_r = -3.0e38f, l_r = 0.f;

  for (int kt = t0; kt < t1; ++kt){
    // ---- stage (amortized over 8 waves): K rows w*8..w*8+7; V dh w*8..w*8+7 ----
    {
      int key = w * 8 + (lane >> 3);
      int sc = (lane & 7) ^ (lane >> 3);
      gload_lds16(base + (long)(kt * 64 + key) * 3072 + 1024 + h * 64 + sc * 8,
                  Kl + (w * 8) * 128);
      uint4 vvv = *reinterpret_cast<const uint4*>(base + (long)(kt * 64 + lane) * 3072 + 2048 + h * 64 + w * 8);
      const unsigned short* vs = reinterpret_cast<const unsigned short*>(&vvv);
      #pragma unroll
      for (int e = 0; e < 8; ++e){
        int dh = w * 8 + e;
        *reinterpret_cast<unsigned short*>(Vt + dh * 128 + ((((lane >> 3) ^ (dh & 7))) << 4) + (lane & 7) * 2) = vs[e];
      }
    }
    __syncthreads();

    if (kt <= KTw){
      bool diag = (kt == KTw);

      f32x16 sa[2];
      __builtin_amdgcn_s_setprio(1);
      #pragma unroll
      for (int kb = 0; kb < 2; ++kb){
        #pragma unroll
        for (int r = 0; r < 16; ++r) sa[kb][r] = 0.f;
        int row = kb * 32 + l31;
        #pragma unroll
        for (int i2 = 0; i2 < 4; ++i2){
          bf16x8 kf = *reinterpret_cast<const bf16x8*>(
              Kl + row * 128 + ((((i2 << 1) | hi) ^ (l31 & 7)) << 4));
          sa[kb] = MFMA32(kf, qf[i2], sa[kb]);
        }
      }
      __builtin_amdgcn_s_setprio(0);

      float pv[32];
      #pragma unroll
      for (int kb = 0; kb < 2; ++kb)
        #pragma unroll
        for (int r = 0; r < 16; ++r) pv[kb * 16 + r] = sa[kb][r];

      if (diag){
        int qg = qbase + l31;
        #pragma unroll
        for (int kb = 0; kb < 2; ++kb)
          #pragma unroll
          for (int r = 0; r < 16; ++r){
            int kg = kt * 64 + kb * 32 + (r & 3) + ((r >> 2) << 3) + (hi << 2);
            if (kg > qg) pv[kb * 16 + r] = -3.0e38f;
          }
      }

      float mt[16];
      #pragma unroll
      for (int r = 0; r < 16; ++r) mt[r] = fmaxf(pv[r], pv[r + 16]);
      #pragma unroll
      for (int r = 0; r < 8; ++r) mt[r] = fmaxf(mt[r], mt[r + 8]);
      #pragma unroll
      for (int r = 0; r < 4; ++r) mt[r] = fmaxf(mt[r], mt[r + 4]);
      float mx = fmaxf(fmaxf(mt[0], mt[1]), fmaxf(mt[2], mt[3]));
      mx = fmaxf(mx, __shfl_xor(mx, 32, 64));

      float scl;
      if (__all(mx <= m_r + 44.0f)){
        scl = 1.f;
      } else {
        float mnew = fmaxf(m_r, mx);
        scl = exp2f((m_r - mnew) * CEXP);
        m_r = mnew;
        #pragma unroll
        for (int d = 0; d < 2; ++d)
          #pragma unroll
          for (int r = 0; r < 16; ++r) oacc[d][r] *= scl;
      }
      float mn_c = m_r * CEXP;
      float rs0 = 0.f, rs1 = 0.f, rs2 = 0.f, rs3 = 0.f;
      #pragma unroll
      for (int r = 0; r < 32; r += 4){
        float e0 = exp2f(__builtin_fmaf(pv[r    ], CEXP, -mn_c)); pv[r    ] = e0; rs0 += e0;
        float e1 = exp2f(__builtin_fmaf(pv[r + 1], CEXP, -mn_c)); pv[r + 1] = e1; rs1 += e1;
        float e2 = exp2f(__builtin_fmaf(pv[r + 2], CEXP, -mn_c)); pv[r + 2] = e2; rs2 += e2;
        float e3 = exp2f(__builtin_fmaf(pv[r + 3], CEXP, -mn_c)); pv[r + 3] = e3; rs3 += e3;
      }
      float rs = (rs0 + rs1) + (rs2 + rs3);
      rs += __shfl_xor(rs, 32, 64);
      l_r = l_r * scl + rs;

      bf16x8 pa[4];
      #pragma unroll
      for (int kb = 0; kb < 2; ++kb){
        unsigned W[4][2], X[4][2];
        #pragma unroll
        for (int u = 0; u < 4; ++u){
          W[u][0] = pkbf(pv[kb * 16 + 4 * u + 0], pv[kb * 16 + 4 * u + 1]);
          W[u][1] = pkbf(pv[kb * 16 + 4 * u + 2], pv[kb * 16 + 4 * u + 3]);
        }
        #pragma unroll
        for (int u = 0; u < 4; ++u){
          X[u][0] = (unsigned)__shfl_xor((int)W[u][0], 32, 64);
          X[u][1] = (unsigned)__shfl_xor((int)W[u][1], 32, 64);
        }
        #pragma unroll
        for (int t2 = 0; t2 < 2; ++t2){
          int u0 = 2 * t2, u1 = u0 + 1;
          uint4v wt;
          wt.x = hi ? X[u1][0] : W[u0][0];
          wt.y = hi ? X[u1][1] : W[u0][1];
          wt.z = hi ? W[u1][0] : X[u0][0];
          wt.w = hi ? W[u1][1] : X[u0][1];
          pa[kb * 2 + t2] = __builtin_bit_cast(bf16x8, wt);
        }
      }
      __builtin_amdgcn_s_setprio(1);
      #pragma unroll
      for (int db = 0; db < 2; ++db){
        int row = db * 32 + l31;
        #pragma unroll
        for (int t = 0; t < 4; ++t){
          bf16x8 vf = *reinterpret_cast<const bf16x8*>(
              Vt + row * 128 + ((((t << 1) | hi) ^ (l31 & 7)) << 4));
          oacc[db] = MFMA32(vf, pa[t], oacc[db]);
        }
      }
      __builtin_amdgcn_s_setprio(0);
    }
    __syncthreads();
  }

  unsigned short* Oq = Op + (long)pidx * 16384 + (w * 32 + l31) * 64;
  #pragma unroll
  for (int db = 0; db < 2; ++db)
    #pragma unroll
    for (int r4 = 0; r4 < 4; ++r4){
      ushort4 o;
      o.x = f2bf(oacc[db][r4 * 4 + 0]);
      o.y = f2bf(oacc[db][r4 * 4 + 1]);
      o.z = f2bf(oacc[db][r4 * 4 + 2]);
      o.w = f2bf(oacc[db][r4 * 4 + 3]);
      *reinterpret_cast<ushort4*>(Oq + db * 32 + r4 * 8 + hi * 4) = o;
    }
  if (hi == 0){
    float2 v; v.x = m_r; v.y = l_r;
    *reinterpret_cast<float2*>(ml + ((long)pidx * 256 + w * 32 + l31) * 2) = v;
  }
}

// ---------------- merge the nspl kv-parts (1024 blocks; mid covers 256 q rows) ----------------
__global__ __launch_bounds__(256) void k_amerge(const unsigned short* __restrict__ Op,
                                                const float* __restrict__ ml,
                                                unsigned short* __restrict__ ao,
                                                int nspl){
  const float CEXP = 0.18033688011112042f;
  int mid = blockIdx.x >> 2;             // [0,256) = (g, qpair)
  int quarter = blockIdx.x & 3;
  int g = mid >> 3, qpair = mid & 7;
  int b = g >> 4, h = g & 15;
  const unsigned short* O0 = Op + (long)mid * nspl * 16384;
  const float* mlb = ml + (long)mid * nspl * 512;
  int t = threadIdx.x;
  #pragma unroll
  for (int i = 0; i < 4; ++i){
    int idx4 = quarter * 1024 + i * 256 + t;   // [0,4096) units of 4 elems
    int q = idx4 >> 4, c4 = (idx4 & 15) * 4;
    float m0 = mlb[q * 2],       l0 = mlb[q * 2 + 1];
    float m1 = mlb[512 + q * 2], l1 = mlb[512 + q * 2 + 1];
    float m2 = -3.0e38f, l2 = 0.f, m3 = -3.0e38f, l3 = 0.f;
    if (nspl == 4){
      m2 = mlb[1024 + q * 2]; l2 = mlb[1024 + q * 2 + 1];
      m3 = mlb[1536 + q * 2]; l3 = mlb[1536 + q * 2 + 1];
    }
    float mm = fmaxf(fmaxf(m0, m1), fmaxf(m2, m3));
    float s0 = exp2f((m0 - mm) * CEXP), s1 = exp2f((m1 - mm) * CEXP);
    float s2 = exp2f((m2 - mm) * CEXP), s3 = exp2f((m3 - mm) * CEXP);
    float linv = 1.f / (l0 * s0 + l1 * s1 + l2 * s2 + l3 * s3);
    s0 *= linv; s1 *= linv; s2 *= linv; s3 *= linv;
    ushort4 a = *reinterpret_cast<const ushort4*>(O0 + q * 64 + c4);
    ushort4 c = *reinterpret_cast<const ushort4*>(O0 + 16384 + q * 64 + c4);
    ushort4 a2 = {0,0,0,0}, a3 = {0,0,0,0};
    if (nspl == 4){
      a2 = *reinterpret_cast<const ushort4*>(O0 + 32768 + q * 64 + c4);
      a3 = *reinterpret_cast<const ushort4*>(O0 + 49152 + q * 64 + c4);
    }
    ushort4 o;
    o.x = f2bf(bf2f(a.x) * s0 + bf2f(c.x) * s1 + bf2f(a2.x) * s2 + bf2f(a3.x) * s3);
    o.y = f2bf(bf2f(a.y) * s0 + bf2f(c.y) * s1 + bf2f(a2.y) * s2 + bf2f(a3.y) * s3);
    o.z = f2bf(bf2f(a.z) * s0 + bf2f(c.z) * s1 + bf2f(a2.z) * s2 + bf2f(a3.z) * s3);
    o.w = f2bf(bf2f(a.w) * s0 + bf2f(c.w) * s1 + bf2f(a2.w) * s2 + bf2f(a3.w) * s3);
    *reinterpret_cast<ushort4*>(ao + ((long)b * 2048 + qpair * 256 + q) * 1024 + h * 64 + c4) = o;
  }
}

// ---------------- launch ----------------
extern "C" void kernel_launch(void* const* d_in, const int* in_sizes, int n_in,
                              void* d_out, int out_size, void* d_ws, size_t ws_size,
                              hipStream_t stream){
  (void)in_sizes; (void)n_in; (void)out_size;
  const float* x    = (const float*)d_in[0];
  const float* A    = (const float*)d_in[1];
  const float* Bs   = (const float*)d_in[2];
  const float* Wimp = (const float*)d_in[3];
  const float* Wr   = (const float*)d_in[4];
  const float* cn   = (const float*)d_in[5];
  const float* Wq   = (const float*)d_in[6];
  const float* Wk   = (const float*)d_in[7];
  const float* Wv   = (const float*)d_in[8];
  const float* Wo   = (const float*)d_in[9];
  float* out = (float*)d_out;
  char* ws = (char*)d_ws;

  int nspl, nsh;
  {
    size_t tot4 = (size_t)512*4*16384 + (size_t)512*4*1024 + 25165824 + 2097152 + 2800000;
    if (ws_size >= tot4){ nspl = 4; nsh = 2; } else { nspl = 2; nsh = 1; }
  }
  size_t opart_b = (size_t)512 * nspl * 16384;   // == 256*nspl*32768
  size_t ml_off  = opart_b;
  size_t qkv_off = ml_off + (size_t)512 * nspl * 1024;
  size_t wo_off  = qkv_off + 25165824;
  size_t ext     = wo_off + 2097152;

  unsigned short* Opart = (unsigned short*)(ws);
  float*          mlbuf = (float*)(ws + ml_off);
  unsigned short* qkvb  = (unsigned short*)(ws + qkv_off);
  float*          hpp   = (float*)(ws + qkv_off);
  unsigned short* aob   = (unsigned short*)(ws + qkv_off);
  unsigned short* wo_t  = (unsigned short*)(ws + wo_off);
  unsigned short* xb16  = (unsigned short*)(ws + 0);
  float*          rpp   = (float*)(ws + 8388608);
  unsigned short* sct   = (unsigned short*)(ws + ext);
  float*          xbt   = (float*)(ws + ext + 524288);
  float*          lbuf  = (float*)(ws + ext + 548864);
  float*          nwp   = (float*)(ws + ext + 565248);
  float*          hfin  = (float*)(ws + ext + 573440);
  unsigned short* wqkv  = (unsigned short*)(ws + ext + 577536);
  unsigned short* wrt   = (unsigned short*)(ws + ext + 1363968);
  unsigned short* hcomp = (unsigned short*)(ws + ext + 1626112);

  k_conv<<<5696, 256, 0, stream>>>(x, Wq, Wk, Wv, Wo, Wr, Bs, xb16, wqkv, wo_t, wrt, xbt);
  k_gemmsk<<<dim3(1, 32, 5), 256, 0, stream>>>(xb16, wrt, rpp, 4096, 128, 1024, 256, 0, 0,
                                               1, xbt, A, hfin);
  k_logits<<<256, 256, 0, stream>>>(x, hfin, Wimp, lbuf);
  k_nwpart<<<32, 256, 0, stream>>>(rpp, lbuf, nwp);
  k_sc<<<128, 256, 0, stream>>>(cn, nwp, sct);
  k_gemmsk<<<dim3(1, 16, 8), 256, 0, stream>>>(xb16, sct, hpp, 2048, 128, 1024, 256,
                                               2048L * 1024, 128L * 1024, 0, nullptr, nullptr, nullptr);
  k_hred<<<512, 256, 0, stream>>>(hpp, hcomp);
  k_gemm<1><<<dim3(24, 16, 2), 256, 0, stream>>>(hcomp, wqkv, qkvb, 2048, 3072, 128,
                                                 2048L * 128, 0, 2048L * 3072);
  k_attn<<<dim3(256 * nspl), 512, 0, stream>>>(qkvb, Opart, mlbuf, nspl, nsh);
  k_amerge<<<dim3(1024), 256, 0, stream>>>(Opart, mlbuf, aob, nspl);
  k_gemm64<<<dim3(16, 32), 256, 0, stream>>>(aob, wo_t, out, 4096, 1024, 1024);
}

// Round 16
// 165.176 us; speedup vs baseline: 1.0996x; 1.0996x over previous
//
#include <hip/hip_runtime.h>
#include <hip/hip_bf16.h>

// ---------------- common types / helpers ----------------
typedef __bf16 bf16x8 __attribute__((ext_vector_type(8)));
typedef float  f32x4  __attribute__((ext_vector_type(4)));
typedef float  f32x16 __attribute__((ext_vector_type(16)));
typedef unsigned int uint4v __attribute__((ext_vector_type(4)));

__device__ __forceinline__ unsigned short f2bf(float f){
  union { float f; unsigned int u; } v; v.f = f;
  unsigned int r = (v.u + 0x7FFFu + ((v.u >> 16) & 1u)) >> 16;
  return (unsigned short)r;
}

__device__ __forceinline__ float bf2f(unsigned short u){
  union { unsigned int i; float f; } v; v.i = ((unsigned int)u) << 16; return v.f;
}

__device__ __forceinline__ unsigned pkbf(float a, float b){
  unsigned r;
  asm("v_cvt_pk_bf16_f32 %0, %1, %2" : "=v"(r) : "v"(a), "v"(b));
  return r;
}

__device__ __forceinline__ void gload_lds16(const void* g, void* l){
  __builtin_amdgcn_global_load_lds(
      (const __attribute__((address_space(1))) unsigned int*)g,
      (__attribute__((address_space(3))) unsigned int*)l, 16, 0, 0);
}

#define MFMA16(a,b,c) __builtin_amdgcn_mfma_f32_16x16x32_bf16((a),(b),(c),0,0,0)
#define MFMA32(a,b,c) __builtin_amdgcn_mfma_f32_32x32x16_bf16((a),(b),(c),0,0,0)

// ---------------- fused: x->bf16, weights->bf16, AND xB (last 32 rows) ----------------
__global__ void k_conv(const float* __restrict__ x,
                       const float* __restrict__ Wq, const float* __restrict__ Wk,
                       const float* __restrict__ Wv, const float* __restrict__ Wo,
                       const float* __restrict__ Wr, const float* __restrict__ Bs,
                       unsigned short* __restrict__ xb16,
                       unsigned short* __restrict__ wqkv, unsigned short* __restrict__ wo,
                       unsigned short* __restrict__ wrt, float* __restrict__ xbt){
  int bid = blockIdx.x;
  if (bid >= 5632){
    int bb = (bid - 5632) >> 5, t = (bid - 5632) & 31;
    int tid = threadIdx.x, n = tid & 63, p = tid >> 6;
    const float* xr = x + ((long)bb * 2048 + 2016 + t) * 1024 + p * 256;
    const float* Bp = Bs + (p * 256) * 64 + n;
    float a0 = 0.f, a1 = 0.f, a2 = 0.f, a3 = 0.f;
    #pragma unroll 4
    for (int d = 0; d < 256; d += 4){
      float4 xv = *reinterpret_cast<const float4*>(xr + d);
      a0 += xv.x * Bp[(d    ) * 64];
      a1 += xv.y * Bp[(d + 1) * 64];
      a2 += xv.z * Bp[(d + 2) * 64];
      a3 += xv.w * Bp[(d + 3) * 64];
    }
    __shared__ float red[4][64];
    red[p][n] = (a0 + a1) + (a2 + a3);
    __syncthreads();
    if (tid < 64){
      float s = red[0][tid] + red[1][tid] + red[2][tid] + red[3][tid];
      xbt[(bb * 32 + t) * 64 + tid] = s;
    }
    return;
  }
  if (bid < 4096){
    int i = (bid * 256 + threadIdx.x) * 4;
    float4 v = *reinterpret_cast<const float4*>(x + i);
    ushort4 r; r.x = f2bf(v.x); r.y = f2bf(v.y); r.z = f2bf(v.z); r.w = f2bf(v.w);
    *reinterpret_cast<ushort4*>(xb16 + i) = r;
    return;
  }
  int j = ((bid - 4096) * 256 + threadIdx.x) * 4;
  if (j < 393216){
    const float* s;
    if (j < 131072) s = Wq + j; else if (j < 262144) s = Wk + (j - 131072); else s = Wv + (j - 262144);
    float4 v = *reinterpret_cast<const float4*>(s);
    ushort4 r; r.x = f2bf(v.x); r.y = f2bf(v.y); r.z = f2bf(v.z); r.w = f2bf(v.w);
    *reinterpret_cast<ushort4*>(wqkv + j) = r;
  } else if (j < 1441792){
    int jj = j - 393216;
    float4 v = *reinterpret_cast<const float4*>(Wo + jj);
    ushort4 r; r.x = f2bf(v.x); r.y = f2bf(v.y); r.z = f2bf(v.z); r.w = f2bf(v.w);
    *reinterpret_cast<ushort4*>(wo + jj) = r;
  } else {
    int jj = j - 1441792;
    int n = jj >> 10, d = jj & 1023;
    ushort4 r;
    if (n < 64){
      float4 v = *reinterpret_cast<const float4*>(Wr + n * 1024 + d);
      r.x = f2bf(v.x); r.y = f2bf(v.y); r.z = f2bf(v.z); r.w = f2bf(v.w);
    } else { r.x = 0; r.y = 0; r.z = 0; r.w = 0; }
    *reinterpret_cast<ushort4*>(wrt + jj) = r;
  }
}

// ---------------- generic bf16 GEMM: C[M,N] = A[M,K] * Bt[N,K]^T (128x128) ----------------
template<int CBF16>
__global__ __launch_bounds__(256) void k_gemm(
    const unsigned short* __restrict__ A, const unsigned short* __restrict__ Bt,
    void* __restrict__ Cv, int M, int N, int K,
    long sA, long sB, long sC)
{
  __shared__ __align__(16) unsigned short Al[128 * 64];
  __shared__ __align__(16) unsigned short Bl[128 * 64];
  const int tid = threadIdx.x, wv = tid >> 6, lane = tid & 63;
  const int bm = blockIdx.y * 128, bn = blockIdx.x * 128, z = blockIdx.z;
  const unsigned short* Ab = A + (long)z * sA;
  const unsigned short* Bb = Bt + (long)z * sB;
  const f32x4 zero = {0.f, 0.f, 0.f, 0.f};
  f32x4 acc[4][4];
  #pragma unroll
  for (int i = 0; i < 4; ++i)
    #pragma unroll
    for (int j = 0; j < 4; ++j) acc[i][j] = zero;
  const int mo = (wv & 1) * 64, no = (wv >> 1) * 64;

  for (int k0 = 0; k0 < K; k0 += 64){
    __syncthreads();
    #pragma unroll
    for (int i = 0; i < 4; ++i){
      int rr = (wv * 4 + i) * 8 + (lane >> 3);
      gload_lds16(Ab + (long)(bm + rr) * K + k0 + (lane & 7) * 8, &Al[(wv * 4 + i) * 8 * 64]);
      gload_lds16(Bb + (long)(bn + rr) * K + k0 + (lane & 7) * 8, &Bl[(wv * 4 + i) * 8 * 64]);
    }
    __syncthreads();
    #pragma unroll
    for (int ks = 0; ks < 2; ++ks){
      bf16x8 af[4], bfr[4];
      #pragma unroll
      for (int mi = 0; mi < 4; ++mi)
        af[mi] = *reinterpret_cast<const bf16x8*>(&Al[(mo + mi * 16 + (lane & 15)) * 64 + ks * 32 + (lane >> 4) * 8]);
      #pragma unroll
      for (int ni = 0; ni < 4; ++ni)
        bfr[ni] = *reinterpret_cast<const bf16x8*>(&Bl[(no + ni * 16 + (lane & 15)) * 64 + ks * 32 + (lane >> 4) * 8]);
      #pragma unroll
      for (int mi = 0; mi < 4; ++mi)
        #pragma unroll
        for (int ni = 0; ni < 4; ++ni)
          acc[mi][ni] = MFMA16(af[mi], bfr[ni], acc[mi][ni]);
    }
  }

  #pragma unroll
  for (int mi = 0; mi < 4; ++mi)
    #pragma unroll
    for (int ni = 0; ni < 4; ++ni)
      #pragma unroll
      for (int r = 0; r < 4; ++r){
        int row = bm + mo + mi * 16 + (lane >> 4) * 4 + r;
        int col = bn + no + ni * 16 + (lane & 15);
        float v = acc[mi][ni][r];
        if (CBF16) ((unsigned short*)Cv)[(long)z * sC + (long)row * N + col] = f2bf(v);
        else       ((float*)Cv)[(long)z * sC + (long)row * N + col] = v;
      }
}

// ---------------- 128x64-tile GEMM, f32 out (out-projection) ----------------
__global__ __launch_bounds__(256) void k_gemm64(
    const unsigned short* __restrict__ A, const unsigned short* __restrict__ Bt,
    float* __restrict__ C, int M, int N, int K)
{
  __shared__ __align__(16) unsigned short Al[128 * 64];
  __shared__ __align__(16) unsigned short Bl[64 * 64];
  const int tid = threadIdx.x, wv = tid >> 6, lane = tid & 63;
  const int bm = blockIdx.y * 128, bn = blockIdx.x * 64;
  const f32x4 zero = {0.f, 0.f, 0.f, 0.f};
  f32x4 acc[4][2];
  #pragma unroll
  for (int i = 0; i < 4; ++i){ acc[i][0] = zero; acc[i][1] = zero; }
  const int mo = (wv & 1) * 64, no = (wv >> 1) * 32;

  for (int k0 = 0; k0 < K; k0 += 64){
    __syncthreads();
    #pragma unroll
    for (int i = 0; i < 4; ++i){
      int rr = (wv * 4 + i) * 8 + (lane >> 3);
      gload_lds16(A + (long)(bm + rr) * K + k0 + (lane & 7) * 8, &Al[(wv * 4 + i) * 8 * 64]);
    }
    #pragma unroll
    for (int i = 0; i < 2; ++i){
      int rr = (wv * 2 + i) * 8 + (lane >> 3);
      gload_lds16(Bt + (long)(bn + rr) * K + k0 + (lane & 7) * 8, &Bl[(wv * 2 + i) * 8 * 64]);
    }
    __syncthreads();
    #pragma unroll
    for (int ks = 0; ks < 2; ++ks){
      bf16x8 af[4], bfr[2];
      #pragma unroll
      for (int mi = 0; mi < 4; ++mi)
        af[mi] = *reinterpret_cast<const bf16x8*>(&Al[(mo + mi * 16 + (lane & 15)) * 64 + ks * 32 + (lane >> 4) * 8]);
      #pragma unroll
      for (int ni = 0; ni < 2; ++ni)
        bfr[ni] = *reinterpret_cast<const bf16x8*>(&Bl[(no + ni * 16 + (lane & 15)) * 64 + ks * 32 + (lane >> 4) * 8]);
      #pragma unroll
      for (int mi = 0; mi < 4; ++mi)
        #pragma unroll
        for (int ni = 0; ni < 2; ++ni)
          acc[mi][ni] = MFMA16(af[mi], bfr[ni], acc[mi][ni]);
    }
  }

  #pragma unroll
  for (int mi = 0; mi < 4; ++mi)
    #pragma unroll
    for (int ni = 0; ni < 2; ++ni)
      #pragma unroll
      for (int r = 0; r < 4; ++r){
        int row = bm + mo + mi * 16 + (lane >> 4) * 4 + r;
        int col = bn + no + ni * 16 + (lane & 15);
        C[(long)row * N + col] = acc[mi][ni][r];
      }
}

// ---------------- split-K GEMM: f32 partials, 4 splits of K (+ optional fused scan layer) ----------------
__global__ __launch_bounds__(256) void k_gemmsk(
    const unsigned short* __restrict__ A, const unsigned short* __restrict__ Bt,
    float* __restrict__ P, int M, int N, int Kfull, int KS,
    long sA, long sB,
    int do_scan, const float* __restrict__ xbt, const float* __restrict__ Asc,
    float* __restrict__ hfin)
{
  __shared__ __align__(16) unsigned short Al[128 * 64];
  __shared__ __align__(16) unsigned short Bl[128 * 64];
  const int tid = threadIdx.x, wv = tid >> 6, lane = tid & 63;

  if (do_scan && blockIdx.z == 4){
    if (blockIdx.y < 2 && tid < 64){
      int b = blockIdx.y, j = tid;
      float Ac[64];
      #pragma unroll
      for (int i = 0; i < 64; ++i) Ac[i] = Asc[i * 64 + j];
      float* xs = (float*)Al;
      float* hs = xs + 2048;
      #pragma unroll
      for (int t = 0; t < 32; ++t) xs[t * 64 + j] = xbt[(b * 32 + t) * 64 + j];
      hs[j] = xs[j];
      for (int t = 1; t < 32; ++t){
        float a0 = 0.f, a1 = 0.f, a2 = 0.f, a3 = 0.f;
        #pragma unroll
        for (int ii = 0; ii < 16; ++ii){
          float4 h4 = *reinterpret_cast<const float4*>(&hs[ii * 4]);
          a0 += h4.x * Ac[ii * 4 + 0];
          a1 += h4.y * Ac[ii * 4 + 1];
          a2 += h4.z * Ac[ii * 4 + 2];
          a3 += h4.w * Ac[ii * 4 + 3];
        }
        hs[j] = (a0 + a1) + (a2 + a3) + xs[t * 64 + j];
      }
      hfin[b * 64 + j] = hs[j];
    }
    return;
  }

  const int bm = blockIdx.y * 128, bn = blockIdx.x * 128, z = blockIdx.z;
  const int b = z >> 2, s = z & 3;
  const unsigned short* Ab = A + (long)b * sA;
  const unsigned short* Bb = Bt + (long)b * sB;
  float* Pb = P + (long)z * M * N;
  const f32x4 zero = {0.f, 0.f, 0.f, 0.f};
  f32x4 acc[4][4];
  #pragma unroll
  for (int i = 0; i < 4; ++i)
    #pragma unroll
    for (int j = 0; j < 4; ++j) acc[i][j] = zero;
  const int mo = (wv & 1) * 64, no = (wv >> 1) * 64;

  const int k1 = s * KS + KS;
  for (int k0 = s * KS; k0 < k1; k0 += 64){
    __syncthreads();
    #pragma unroll
    for (int i = 0; i < 4; ++i){
      int rr = (wv * 4 + i) * 8 + (lane >> 3);
      gload_lds16(Ab + (long)(bm + rr) * Kfull + k0 + (lane & 7) * 8, &Al[(wv * 4 + i) * 8 * 64]);
      gload_lds16(Bb + (long)(bn + rr) * Kfull + k0 + (lane & 7) * 8, &Bl[(wv * 4 + i) * 8 * 64]);
    }
    __syncthreads();
    #pragma unroll
    for (int ks = 0; ks < 2; ++ks){
      bf16x8 af[4], bfr[4];
      #pragma unroll
      for (int mi = 0; mi < 4; ++mi)
        af[mi] = *reinterpret_cast<const bf16x8*>(&Al[(mo + mi * 16 + (lane & 15)) * 64 + ks * 32 + (lane >> 4) * 8]);
      #pragma unroll
      for (int ni = 0; ni < 4; ++ni)
        bfr[ni] = *reinterpret_cast<const bf16x8*>(&Bl[(no + ni * 16 + (lane & 15)) * 64 + ks * 32 + (lane >> 4) * 8]);
      #pragma unroll
      for (int mi = 0; mi < 4; ++mi)
        #pragma unroll
        for (int ni = 0; ni < 4; ++ni)
          acc[mi][ni] = MFMA16(af[mi], bfr[ni], acc[mi][ni]);
    }
  }

  #pragma unroll
  for (int mi = 0; mi < 4; ++mi)
    #pragma unroll
    for (int ni = 0; ni < 4; ++ni)
      #pragma unroll
      for (int r = 0; r < 4; ++r){
        int row = bm + mo + mi * 16 + (lane >> 4) * 4 + r;
        int col = bn + no + ni * 16 + (lane & 15);
        Pb[(long)row * N + col] = acc[mi][ni][r];
      }
}

// ---------------- reduce hcomp partials (4 splits) -> bf16 ----------------
__global__ __launch_bounds__(256) void k_hred(const float* __restrict__ hpp,
                                              unsigned short* __restrict__ hcomp){
  int i4 = (blockIdx.x * 256 + threadIdx.x) * 4;
  int b = i4 >> 18;
  int rem = i4 & 262143;
  const float* p = hpp + (long)(b * 4) * 262144 + rem;
  f32x4 v = *reinterpret_cast<const f32x4*>(p);
  v += *reinterpret_cast<const f32x4*>(p + 262144);
  v += *reinterpret_cast<const f32x4*>(p + 524288);
  v += *reinterpret_cast<const f32x4*>(p + 786432);
  ushort4 o; o.x = f2bf(v[0]); o.y = f2bf(v[1]); o.z = f2bf(v[2]); o.w = f2bf(v[3]);
  *reinterpret_cast<ushort4*>(hcomp + (long)b * 262144 + rem) = o;
}

// ---------------- importance logits (with fused h_proj recompute per block) ----------------
__global__ __launch_bounds__(256) void k_logits(const float* __restrict__ x,
                                                const float* __restrict__ hfin,
                                                const float* __restrict__ Wimp,
                                                float* __restrict__ l){
  int tid = threadIdx.x, lane = tid & 63, wv = tid >> 6;
  int rowbase = blockIdx.x * 16;
  int b = rowbase >> 11;
  __shared__ float hs[64];
  __shared__ float hpl[1024];
  if (tid < 64) hs[tid] = hfin[b * 64 + tid];
  __syncthreads();
  #pragma unroll
  for (int e = 0; e < 4; ++e){
    int d = tid * 4 + e;
    const float* wr = Wimp + (long)d * 64;
    float a0 = 0.f, a1 = 0.f, a2 = 0.f, a3 = 0.f;
    #pragma unroll
    for (int k = 0; k < 64; k += 4){
      float4 w4 = *reinterpret_cast<const float4*>(wr + k);
      float4 h4 = *reinterpret_cast<const float4*>(&hs[k]);
      a0 += w4.x * h4.x; a1 += w4.y * h4.y; a2 += w4.z * h4.z; a3 += w4.w * h4.w;
    }
    hpl[d] = (a0 + a1) + (a2 + a3);
  }
  __syncthreads();
  float hp[16];
  #pragma unroll
  for (int i = 0; i < 16; ++i) hp[i] = hpl[i * 64 + lane];
  for (int rr = 0; rr < 4; ++rr){
    int row = rowbase + wv * 4 + rr;
    const float* xr = x + (long)row * 1024;
    float acc = 0.f;
    #pragma unroll
    for (int i = 0; i < 16; ++i) acc += xr[i * 64 + lane] * hp[i];
    #pragma unroll
    for (int o = 32; o; o >>= 1) acc += __shfl_xor(acc, o, 64);
    if (lane == 0) l[row] = acc;
  }
}

// ---------------- nw partials (64 blocks; fused importance softmax + router softmax) ----------------
__global__ void k_nwpart(const float* __restrict__ rpp, const float* __restrict__ lbuf,
                         float* __restrict__ nwp){
  int bid = blockIdx.x; int b = bid >> 5, chunk = bid & 31;
  int tid = threadIdx.x, wv = tid >> 6, lane = tid & 63;
  __shared__ float wred[4], wsum[4];
  __shared__ float red[4][64];
  const float* lr = lbuf + b * 2048;
  float4 va = *reinterpret_cast<const float4*>(lr + tid * 8);
  float4 vb = *reinterpret_cast<const float4*>(lr + tid * 8 + 4);
  float mx8 = fmaxf(fmaxf(fmaxf(va.x, va.y), fmaxf(va.z, va.w)),
                    fmaxf(fmaxf(vb.x, vb.y), fmaxf(vb.z, vb.w)));
  #pragma unroll
  for (int o = 32; o; o >>= 1) mx8 = fmaxf(mx8, __shfl_xor(mx8, o, 64));
  if (lane == 0) wred[wv] = mx8;
  __syncthreads();
  float M = fmaxf(fmaxf(wred[0], wred[1]), fmaxf(wred[2], wred[3]));
  float se = __expf(va.x - M) + __expf(va.y - M) + __expf(va.z - M) + __expf(va.w - M)
           + __expf(vb.x - M) + __expf(vb.y - M) + __expf(vb.z - M) + __expf(vb.w - M);
  #pragma unroll
  for (int o = 32; o; o >>= 1) se += __shfl_xor(se, o, 64);
  if (lane == 0) wsum[wv] = se;
  __syncthreads();
  float inv = 1.f / (wsum[0] + wsum[1] + wsum[2] + wsum[3]);

  float accn = 0.f;
  for (int t = 0; t < 16; ++t){
    int s = chunk * 64 + wv * 16 + t;
    long off = ((long)b * 2048 + s) * 128 + lane;
    float v = rpp[off] + rpp[off + 524288] + rpp[off + 1048576] + rpp[off + 1572864];
    float mx = v;
    #pragma unroll
    for (int o = 32; o; o >>= 1) mx = fmaxf(mx, __shfl_xor(mx, o, 64));
    float e = __expf(v - mx);
    float sm = e;
    #pragma unroll
    for (int o = 32; o; o >>= 1) sm += __shfl_xor(sm, o, 64);
    float impv = __expf(lr[s] - M) * inv;
    accn += impv * (e / sm);
  }
  red[wv][lane] = accn;
  __syncthreads();
  if (wv == 0){
    float t = red[0][lane] + red[1][lane] + red[2][lane] + red[3][lane];
    nwp[bid * 64 + lane] = t;
  }
}

// ---------------- shared_compress^T (with fused nw normalization; 32 chunks) ----------------
__global__ void k_sc(const float* __restrict__ cn, const float* __restrict__ nwp,
                     unsigned short* __restrict__ sct){
  int tid = threadIdx.x;
  long idx = (long)blockIdx.x * 256 + tid;
  int d = (int)(idx >> 5); int r0 = (int)(idx & 31) * 4;
  __shared__ float nws[128];
  if (tid < 128){
    int bb = tid >> 6, nn = tid & 63;
    float a = 0.f;
    #pragma unroll
    for (int c = 0; c < 32; ++c) a += nwp[(bb * 32 + c) * 64 + nn];
    float tot = a;
    #pragma unroll
    for (int o = 32; o; o >>= 1) tot += __shfl_xor(tot, o, 64);
    nws[tid] = a / (tot + 1e-8f);
  }
  __syncthreads();
  f32x4 a0 = {0.f,0.f,0.f,0.f}, a1 = {0.f,0.f,0.f,0.f};
  for (int n = 0; n < 64; ++n){
    f32x4 c = *reinterpret_cast<const f32x4*>(&cn[((long)n * 1024 + d) * 128 + r0]);
    a0 += nws[n] * c;
    a1 += nws[64 + n] * c;
  }
  #pragma unroll
  for (int e = 0; e < 4; ++e){
    sct[(long)(r0 + e) * 1024 + d]        = f2bf(a0[e]);
    sct[(long)(128 + r0 + e) * 1024 + d]  = f2bf(a1[e]);
  }
}

// ---------------- flash attention: nspl-way KV split, tree-reduced softmax (round-14 proven) ----------------
__global__ __launch_bounds__(256, 4) void k_attn(const unsigned short* __restrict__ qkv,
                                                 unsigned short* __restrict__ Op,
                                                 float* __restrict__ ml,
                                                 int nspl, int nsh){
  __shared__ __align__(16) unsigned short KlA[64 * 64];
  __shared__ __align__(16) unsigned short VtA[64 * 64];
  char* Kl = (char*)KlA;
  char* Vt = (char*)VtA;
  const int tid = threadIdx.x, wq = tid >> 6, lane = tid & 63;
  const int l31 = lane & 31, hi = lane >> 5;
  const float CEXP = 0.18033688011112042f;  // 0.125 * log2(e)

  int li = blockIdx.x;
  int j = li & 7, m = li >> 3;
  int g = j * 4 + (m & 3);
  int r5 = m >> 2;
  int k5 = r5 & 7, sel = r5 >> 3;
  int qb = (sel < nspl) ? (15 - k5) : k5;
  int part = (sel < nspl) ? sel : (sel - nspl);
  int h = g & 15, b = g >> 4;
  int pidx = (g * 16 + qb) * nspl + part;

  int T = 2 * qb + 2;
  int t0 = (part * T) >> nsh;
  int t1 = ((part + 1) * T) >> nsh;

  int qbase = qb * 128 + wq * 32;
  int KTw = qbase >> 6;
  const unsigned short* base = qkv + (long)b * 2048 * 3072;

  bf16x8 qf[4];
  #pragma unroll
  for (int i = 0; i < 4; ++i)
    qf[i] = *reinterpret_cast<const bf16x8*>(base + (long)(qbase + l31) * 3072 + h * 64 + i * 16 + hi * 8);

  f32x16 oacc[2];
  #pragma unroll
  for (int d = 0; d < 2; ++d)
    #pragma unroll
    for (int r = 0; r < 16; ++r) oacc[d][r] = 0.f;
  float m_r = -3.0e38f, l_r = 0.f;

  for (int kt = t0; kt < t1; ++kt){
    #pragma unroll
    for (int it = 0; it < 2; ++it){
      int key = it * 32 + wq * 8 + (lane >> 3);
      int sc = (lane & 7) ^ (key & 7);
      gload_lds16(base + (long)(kt * 64 + key) * 3072 + 1024 + h * 64 + sc * 8,
                  Kl + (it * 32 + wq * 8) * 128);
    }
    #pragma unroll
    for (int it = 0; it < 2; ++it){
      int dhg = wq + it * 4;
      uint4 vvv = *reinterpret_cast<const uint4*>(base + (long)(kt * 64 + lane) * 3072 + 2048 + h * 64 + dhg * 8);
      const unsigned short* vs = reinterpret_cast<const unsigned short*>(&vvv);
      #pragma unroll
      for (int e = 0; e < 8; ++e){
        int dh = dhg * 8 + e;
        *reinterpret_cast<unsigned short*>(Vt + dh * 128 + ((((lane >> 3) ^ (dh & 7))) << 4) + (lane & 7) * 2) = vs[e];
      }
    }
    __syncthreads();

    if (kt <= KTw){
      bool diag = (kt == KTw);

      f32x16 sa[2];
      __builtin_amdgcn_s_setprio(1);
      #pragma unroll
      for (int kb = 0; kb < 2; ++kb){
        #pragma unroll
        for (int r = 0; r < 16; ++r) sa[kb][r] = 0.f;
        int row = kb * 32 + l31;
        #pragma unroll
        for (int i2 = 0; i2 < 4; ++i2){
          bf16x8 kf = *reinterpret_cast<const bf16x8*>(
              Kl + row * 128 + ((((i2 << 1) | hi) ^ (l31 & 7)) << 4));
          sa[kb] = MFMA32(kf, qf[i2], sa[kb]);
        }
      }
      __builtin_amdgcn_s_setprio(0);

      float pv[32];
      #pragma unroll
      for (int kb = 0; kb < 2; ++kb)
        #pragma unroll
        for (int r = 0; r < 16; ++r) pv[kb * 16 + r] = sa[kb][r];

      if (diag){
        int qg = qbase + l31;
        #pragma unroll
        for (int kb = 0; kb < 2; ++kb)
          #pragma unroll
          for (int r = 0; r < 16; ++r){
            int kg = kt * 64 + kb * 32 + (r & 3) + ((r >> 2) << 3) + (hi << 2);
            if (kg > qg) pv[kb * 16 + r] = -3.0e38f;
          }
      }

      float mt[16];
      #pragma unroll
      for (int r = 0; r < 16; ++r) mt[r] = fmaxf(pv[r], pv[r + 16]);
      #pragma unroll
      for (int r = 0; r < 8; ++r) mt[r] = fmaxf(mt[r], mt[r + 8]);
      #pragma unroll
      for (int r = 0; r < 4; ++r) mt[r] = fmaxf(mt[r], mt[r + 4]);
      float mx = fmaxf(fmaxf(mt[0], mt[1]), fmaxf(mt[2], mt[3]));
      mx = fmaxf(mx, __shfl_xor(mx, 32, 64));

      float scl;
      if (__all(mx <= m_r + 44.0f)){
        scl = 1.f;
      } else {
        float mnew = fmaxf(m_r, mx);
        scl = exp2f((m_r - mnew) * CEXP);
        m_r = mnew;
        #pragma unroll
        for (int d = 0; d < 2; ++d)
          #pragma unroll
          for (int r = 0; r < 16; ++r) oacc[d][r] *= scl;
      }
      float mn_c = m_r * CEXP;
      float rs0 = 0.f, rs1 = 0.f, rs2 = 0.f, rs3 = 0.f;
      #pragma unroll
      for (int r = 0; r < 32; r += 4){
        float e0 = exp2f(__builtin_fmaf(pv[r    ], CEXP, -mn_c)); pv[r    ] = e0; rs0 += e0;
        float e1 = exp2f(__builtin_fmaf(pv[r + 1], CEXP, -mn_c)); pv[r + 1] = e1; rs1 += e1;
        float e2 = exp2f(__builtin_fmaf(pv[r + 2], CEXP, -mn_c)); pv[r + 2] = e2; rs2 += e2;
        float e3 = exp2f(__builtin_fmaf(pv[r + 3], CEXP, -mn_c)); pv[r + 3] = e3; rs3 += e3;
      }
      float rs = (rs0 + rs1) + (rs2 + rs3);
      rs += __shfl_xor(rs, 32, 64);
      l_r = l_r * scl + rs;

      bf16x8 pa[4];
      #pragma unroll
      for (int kb = 0; kb < 2; ++kb){
        unsigned W[4][2], X[4][2];
        #pragma unroll
        for (int u = 0; u < 4; ++u){
          W[u][0] = pkbf(pv[kb * 16 + 4 * u + 0], pv[kb * 16 + 4 * u + 1]);
          W[u][1] = pkbf(pv[kb * 16 + 4 * u + 2], pv[kb * 16 + 4 * u + 3]);
        }
        #pragma unroll
        for (int u = 0; u < 4; ++u){
          X[u][0] = (unsigned)__shfl_xor((int)W[u][0], 32, 64);
          X[u][1] = (unsigned)__shfl_xor((int)W[u][1], 32, 64);
        }
        #pragma unroll
        for (int t2 = 0; t2 < 2; ++t2){
          int u0 = 2 * t2, u1 = u0 + 1;
          uint4v wt;
          wt.x = hi ? X[u1][0] : W[u0][0];
          wt.y = hi ? X[u1][1] : W[u0][1];
          wt.z = hi ? W[u1][0] : X[u0][0];
          wt.w = hi ? W[u1][1] : X[u0][1];
          pa[kb * 2 + t2] = __builtin_bit_cast(bf16x8, wt);
        }
      }
      __builtin_amdgcn_s_setprio(1);
      #pragma unroll
      for (int db = 0; db < 2; ++db){
        int row = db * 32 + l31;
        #pragma unroll
        for (int t = 0; t < 4; ++t){
          bf16x8 vf = *reinterpret_cast<const bf16x8*>(
              Vt + row * 128 + ((((t << 1) | hi) ^ (l31 & 7)) << 4));
          oacc[db] = MFMA32(vf, pa[t], oacc[db]);
        }
      }
      __builtin_amdgcn_s_setprio(0);
    }
    __syncthreads();
  }

  unsigned short* Oq = Op + (long)pidx * 8192 + (wq * 32 + l31) * 64;
  #pragma unroll
  for (int db = 0; db < 2; ++db)
    #pragma unroll
    for (int r4 = 0; r4 < 4; ++r4){
      ushort4 o;
      o.x = f2bf(oacc[db][r4 * 4 + 0]);
      o.y = f2bf(oacc[db][r4 * 4 + 1]);
      o.z = f2bf(oacc[db][r4 * 4 + 2]);
      o.w = f2bf(oacc[db][r4 * 4 + 3]);
      *reinterpret_cast<ushort4*>(Oq + db * 32 + r4 * 8 + hi * 4) = o;
    }
  if (hi == 0){
    float2 v; v.x = m_r; v.y = l_r;
    *reinterpret_cast<float2*>(ml + ((long)pidx * 128 + wq * 32 + l31) * 2) = v;
  }
}

// ---------------- merge the nspl kv-parts (1024 blocks) ----------------
__global__ __launch_bounds__(256) void k_amerge(const unsigned short* __restrict__ Op,
                                                const float* __restrict__ ml,
                                                unsigned short* __restrict__ ao,
                                                int nspl){
  const float CEXP = 0.18033688011112042f;
  int mid = blockIdx.x >> 1;             // [0,512) = (g, qb)
  int hh = blockIdx.x & 1;
  int g = mid >> 4, qb = mid & 15;
  int b = g >> 4, h = g & 15;
  const unsigned short* O0 = Op + (long)mid * nspl * 8192;
  const float* mlb = ml + (long)mid * nspl * 256;
  int t = threadIdx.x;
  #pragma unroll
  for (int i = 0; i < 4; ++i){
    int idx = hh * 1024 + i * 256 + t;
    int q = idx >> 4, c4 = (idx & 15) * 4;
    float m0 = mlb[q * 2],       l0 = mlb[q * 2 + 1];
    float m1 = mlb[256 + q * 2], l1 = mlb[256 + q * 2 + 1];
    float m2 = -3.0e38f, l2 = 0.f, m3 = -3.0e38f, l3 = 0.f;
    if (nspl == 4){
      m2 = mlb[512 + q * 2]; l2 = mlb[512 + q * 2 + 1];
      m3 = mlb[768 + q * 2]; l3 = mlb[768 + q * 2 + 1];
    }
    float mm = fmaxf(fmaxf(m0, m1), fmaxf(m2, m3));
    float s0 = exp2f((m0 - mm) * CEXP), s1 = exp2f((m1 - mm) * CEXP);
    float s2 = exp2f((m2 - mm) * CEXP), s3 = exp2f((m3 - mm) * CEXP);
    float linv = 1.f / (l0 * s0 + l1 * s1 + l2 * s2 + l3 * s3);
    s0 *= linv; s1 *= linv; s2 *= linv; s3 *= linv;
    ushort4 a = *reinterpret_cast<const ushort4*>(O0 + q * 64 + c4);
    ushort4 c = *reinterpret_cast<const ushort4*>(O0 + 8192 + q * 64 + c4);
    ushort4 a2 = {0,0,0,0}, a3 = {0,0,0,0};
    if (nspl == 4){
      a2 = *reinterpret_cast<const ushort4*>(O0 + 16384 + q * 64 + c4);
      a3 = *reinterpret_cast<const ushort4*>(O0 + 24576 + q * 64 + c4);
    }
    ushort4 o;
    o.x = f2bf(bf2f(a.x) * s0 + bf2f(c.x) * s1 + bf2f(a2.x) * s2 + bf2f(a3.x) * s3);
    o.y = f2bf(bf2f(a.y) * s0 + bf2f(c.y) * s1 + bf2f(a2.y) * s2 + bf2f(a3.y) * s3);
    o.z = f2bf(bf2f(a.z) * s0 + bf2f(c.z) * s1 + bf2f(a2.z) * s2 + bf2f(a3.z) * s3);
    o.w = f2bf(bf2f(a.w) * s0 + bf2f(c.w) * s1 + bf2f(a2.w) * s2 + bf2f(a3.w) * s3);
    *reinterpret_cast<ushort4*>(ao + ((long)b * 2048 + qb * 128 + q) * 1024 + h * 64 + c4) = o;
  }
}

// ---------------- launch ----------------
extern "C" void kernel_launch(void* const* d_in, const int* in_sizes, int n_in,
                              void* d_out, int out_size, void* d_ws, size_t ws_size,
                              hipStream_t stream){
  (void)in_sizes; (void)n_in; (void)out_size;
  const float* x    = (const float*)d_in[0];
  const float* A    = (const float*)d_in[1];
  const float* Bs   = (const float*)d_in[2];
  const float* Wimp = (const float*)d_in[3];
  const float* Wr   = (const float*)d_in[4];
  const float* cn   = (const float*)d_in[5];
  const float* Wq   = (const float*)d_in[6];
  const float* Wk   = (const float*)d_in[7];
  const float* Wv   = (const float*)d_in[8];
  const float* Wo   = (const float*)d_in[9];
  float* out = (float*)d_out;
  char* ws = (char*)d_ws;

  int nspl, nsh;
  {
    size_t tot4 = (size_t)512*4*16384 + (size_t)512*4*1024 + 25165824 + 2097152 + 2800000;
    if (ws_size >= tot4){ nspl = 4; nsh = 2; } else { nspl = 2; nsh = 1; }
  }
  size_t opart_b = (size_t)512 * nspl * 16384;
  size_t ml_off  = opart_b;
  size_t qkv_off = ml_off + (size_t)512 * nspl * 1024;
  size_t wo_off  = qkv_off + 25165824;
  size_t ext     = wo_off + 2097152;

  unsigned short* Opart = (unsigned short*)(ws);
  float*          mlbuf = (float*)(ws + ml_off);
  unsigned short* qkvb  = (unsigned short*)(ws + qkv_off);
  float*          hpp   = (float*)(ws + qkv_off);
  unsigned short* aob   = (unsigned short*)(ws + qkv_off);
  unsigned short* wo_t  = (unsigned short*)(ws + wo_off);
  unsigned short* xb16  = (unsigned short*)(ws + 0);
  float*          rpp   = (float*)(ws + 8388608);
  unsigned short* sct   = (unsigned short*)(ws + ext);               //   524,288
  float*          xbt   = (float*)(ws + ext + 524288);               //    16,384
  float*          lbuf  = (float*)(ws + ext + 540672);               //    16,384
  float*          nwp   = (float*)(ws + ext + 557056);               //    16,384
  float*          hfin  = (float*)(ws + ext + 573440);               //       512
  unsigned short* wqkv  = (unsigned short*)(ws + ext + 573952);      //   786,432
  unsigned short* wrt   = (unsigned short*)(ws + ext + 1360384);     //   262,144
  unsigned short* hcomp = (unsigned short*)(ws + ext + 1622528);     // 1,048,576 (end 2,671,104)

  k_conv<<<5696, 256, 0, stream>>>(x, Wq, Wk, Wv, Wo, Wr, Bs, xb16, wqkv, wo_t, wrt, xbt);
  k_gemmsk<<<dim3(1, 32, 5), 256, 0, stream>>>(xb16, wrt, rpp, 4096, 128, 1024, 256, 0, 0,
                                               1, xbt, A, hfin);
  k_logits<<<256, 256, 0, stream>>>(x, hfin, Wimp, lbuf);
  k_nwpart<<<64, 256, 0, stream>>>(rpp, lbuf, nwp);
  k_sc<<<128, 256, 0, stream>>>(cn, nwp, sct);
  k_gemmsk<<<dim3(1, 16, 8), 256, 0, stream>>>(xb16, sct, hpp, 2048, 128, 1024, 256,
                                               2048L * 1024, 128L * 1024, 0, nullptr, nullptr, nullptr);
  k_hred<<<512, 256, 0, stream>>>(hpp, hcomp);
  k_gemm<1><<<dim3(24, 16, 2), 256, 0, stream>>>(hcomp, wqkv, qkvb, 2048, 3072, 128,
                                                 2048L * 128, 0, 2048L * 3072);
  k_attn<<<dim3(512 * nspl), 256, 0, stream>>>(qkvb, Opart, mlbuf, nspl, nsh);
  k_amerge<<<dim3(1024), 256, 0, stream>>>(Opart, mlbuf, aob, nspl);
  k_gemm64<<<dim3(16, 32), 256, 0, stream>>>(aob, wo_t, out, 4096, 1024, 1024);
}